// Round 1
// baseline (11482.358 us; speedup 1.0000x reference)
//
#include <hip/hip_runtime.h>
#include <math.h>

// Problem dims (fixed)
#define B_ 256
#define L_ 128
#define C_ 256
#define H_ 512
#define TC 16            // time-chunk for precompute staging (ws = ~41MB)
#define NCHUNK (L_/TC)   // 8

// Key algebra:
//  - alpha_t = softmax_c(x_score[b,:]) is INDEPENDENT of t (h/C terms are
//    per-batch scalars across the softmax axis) -> x_tilde fully parallel.
//  - mt    = A_t + h_{t-1} @ Wmh,  A = x@Wmx + (bmx+bmh)   [A parallel]
//  - gates = G_t + mt @ Whm,       G = x@Wih + (bih+bhm)   [G parallel]
// Sequential part = 2 small GEMMs + cell per step, launched per-step.

__device__ __forceinline__ float sigm(float x){ return 1.f/(1.f+expf(-x)); }

// ---------------------------------------------------------------------------
// Kernel 1: alpha = softmax over C of  sum_l x[b,l,c]*Wa_x[l] + ba ;
//           x_tilde[b,l,c] = alpha[b,c] * x[b,l,c]
// grid = B blocks, 256 threads (one per channel c)
// ---------------------------------------------------------------------------
__global__ __launch_bounds__(256) void xtilde_kernel(
    const float* __restrict__ x, const float* __restrict__ Wa,
    const float* __restrict__ ba, float* __restrict__ xt_out)
{
  const int b = blockIdx.x;
  const int c = threadIdx.x;
  const float* Wax = Wa + 2*H_;            // Wa[2H:], length L
  const float* xb  = x + (size_t)b*L_*C_;
  float s = 0.f;
  #pragma unroll 4
  for (int l = 0; l < L_; ++l) s += xb[(size_t)l*C_ + c] * Wax[l];
  s += ba[0];

  __shared__ float red[256];
  red[c] = s; __syncthreads();
  for (int off = 128; off > 0; off >>= 1) {
    if (c < off) red[c] = fmaxf(red[c], red[c+off]);
    __syncthreads();
  }
  const float m = red[0]; __syncthreads();
  const float e = expf(s - m);
  red[c] = e; __syncthreads();
  for (int off = 128; off > 0; off >>= 1) {
    if (c < off) red[c] += red[c+off];
    __syncthreads();
  }
  const float alpha = e / red[0];
  float* ob = xt_out + (size_t)b*L_*C_;
  #pragma unroll 4
  for (int l = 0; l < L_; ++l) ob[(size_t)l*C_ + c] = alpha * xb[(size_t)l*C_ + c];
}

// ---------------------------------------------------------------------------
// Kernel 2: chunked precompute GEMM.  Out[(b*TC+tl), n] =
//     sum_k x[b, t0+tl, k] * W[k, n] + b1[n] + b2[n]
// M = B*TC = 4096, K = C_ = 256, N = 512 (Wmx) or 2048 (Wih)
// 64x64 tile, 256 threads, 4x4 per thread.
// ---------------------------------------------------------------------------
__global__ __launch_bounds__(256) void gemm_precompute(
    const float* __restrict__ x, const float* __restrict__ W,
    const float* __restrict__ b1, const float* __restrict__ b2,
    float* __restrict__ Out, int N, int t0)
{
  constexpr int BM=64, BN=64, BK=16, TM=4, TN=4;
  __shared__ float Xs[BK][BM+1];
  __shared__ float Ws[BK][BN+1];
  const int tid  = threadIdx.x;
  const int row0 = blockIdx.y * BM;
  const int col0 = blockIdx.x * BN;
  const int tx = tid & 15;   // BN/TN = 16
  const int ty = tid >> 4;   // BM/TM = 16
  float acc[TM][TN] = {};

  for (int k0 = 0; k0 < C_; k0 += BK) {
    #pragma unroll
    for (int idx = tid; idx < BM*BK; idx += 256) {
      int m = idx >> 4, kk = idx & 15;
      int gm = row0 + m;
      int b  = gm >> 4;          // /TC
      int tl = gm & 15;          // %TC
      Xs[kk][m] = x[((size_t)b*L_ + t0 + tl)*C_ + k0 + kk];
    }
    #pragma unroll
    for (int idx = tid; idx < BK*BN; idx += 256) {
      int kk = idx >> 6, n = idx & 63;
      Ws[kk][n] = W[(size_t)(k0+kk)*N + col0 + n];
    }
    __syncthreads();
    #pragma unroll
    for (int kk = 0; kk < BK; ++kk) {
      float xr[TM], wr[TN];
      #pragma unroll
      for (int i=0;i<TM;++i) xr[i] = Xs[kk][ty*TM+i];
      #pragma unroll
      for (int j=0;j<TN;++j) wr[j] = Ws[kk][tx*TN+j];
      #pragma unroll
      for (int i=0;i<TM;++i)
        #pragma unroll
        for (int j=0;j<TN;++j) acc[i][j] += xr[i]*wr[j];
    }
    __syncthreads();
  }
  #pragma unroll
  for (int i=0;i<TM;++i) {
    int r = row0 + ty*TM + i;
    #pragma unroll
    for (int j=0;j<TN;++j) {
      int cc = col0 + tx*TN + j;
      Out[(size_t)r*N + cc] = acc[i][j] + b1[cc] + b2[cc];
    }
  }
}

// ---------------------------------------------------------------------------
// Kernel 3: mt[b, n] = A_chunk[b*TC+tl, n] + sum_k h_{t-1}[b,k] * Wmh[k,n]
// M = B = 256, K = 512 (or 0 at t=0), N = 512.  32x32 tile, 2x2/thread.
// Hprev points at hseq + (t-1)*H ; batch-row stride = L*H.
// ---------------------------------------------------------------------------
__global__ __launch_bounds__(256) void mt_kernel(
    const float* __restrict__ Hprev, const float* __restrict__ Wmh,
    const float* __restrict__ Achunk, int tl,
    float* __restrict__ Mt, int Kdim)
{
  constexpr int BM=32, BN=32, BK=32;
  __shared__ float Xs[BK][BM+1];
  __shared__ float Ws[BK][BN+1];
  const int tid  = threadIdx.x;
  const int row0 = blockIdx.y * BM;
  const int col0 = blockIdx.x * BN;
  const int tx = tid & 15;
  const int ty = tid >> 4;
  float acc[2][2] = {};

  for (int k0 = 0; k0 < Kdim; k0 += BK) {
    #pragma unroll
    for (int idx = tid; idx < BM*BK; idx += 256) {
      int m = idx >> 5, kk = idx & 31;
      Xs[kk][m] = Hprev[(size_t)(row0+m)*(L_*H_) + k0 + kk];
    }
    #pragma unroll
    for (int idx = tid; idx < BK*BN; idx += 256) {
      int kk = idx >> 5, n = idx & 31;
      Ws[kk][n] = Wmh[(size_t)(k0+kk)*H_ + col0 + n];
    }
    __syncthreads();
    #pragma unroll
    for (int kk = 0; kk < BK; ++kk) {
      float x0 = Xs[kk][ty*2], x1 = Xs[kk][ty*2+1];
      float w0 = Ws[kk][tx*2], w1 = Ws[kk][tx*2+1];
      acc[0][0] += x0*w0; acc[0][1] += x0*w1;
      acc[1][0] += x1*w0; acc[1][1] += x1*w1;
    }
    __syncthreads();
  }
  #pragma unroll
  for (int i=0;i<2;++i) {
    int r = row0 + ty*2 + i;
    #pragma unroll
    for (int j=0;j<2;++j) {
      int cc = col0 + tx*2 + j;
      Mt[(size_t)r*H_ + cc] = acc[i][j] + Achunk[((size_t)r*TC + tl)*H_ + cc];
    }
  }
}

// ---------------------------------------------------------------------------
// Kernel 4: gates GEMM + LSTM cell, fused.
// Block covers 32 batch rows x 16 h-columns; the 4 gate columns
// {j, H+j, 2H+j, 3H+j} are computed together so the cell applies in-block.
// gates[b, g*H+j] = G_chunk[b*TC+tl, g*H+j] + sum_k mt[b,k]*Whm[k, g*H+j]
// ---------------------------------------------------------------------------
__global__ __launch_bounds__(256) void gates_cell_kernel(
    const float* __restrict__ Mt, const float* __restrict__ Whm,
    const float* __restrict__ Gchunk, int tl,
    const float* __restrict__ Cprev,   // cseq + (t-1)*H, or nullptr at t=0
    float* __restrict__ Hout, float* __restrict__ Cout)
{
  constexpr int BM=32, BK=16;
  __shared__ float Xs[BK][BM+1];
  __shared__ float Ws[BK][65];   // col c = gate*16 + jj
  const int tid  = threadIdx.x;
  const int row0 = blockIdx.y * BM;
  const int j0   = blockIdx.x * 16;
  const int tx = tid & 15;   // jj
  const int ty = tid >> 4;   // row pair
  float acc[2][4] = {};

  for (int k0 = 0; k0 < H_; k0 += BK) {
    #pragma unroll
    for (int idx = tid; idx < BM*BK; idx += 256) {
      int m = idx >> 4, kk = idx & 15;
      Xs[kk][m] = Mt[(size_t)(row0+m)*H_ + k0 + kk];
    }
    #pragma unroll
    for (int idx = tid; idx < BK*64; idx += 256) {
      int kk = idx >> 6, c = idx & 63;
      int gate = c >> 4, jj = c & 15;
      Ws[kk][c] = Whm[(size_t)(k0+kk)*(4*H_) + (size_t)gate*H_ + j0 + jj];
    }
    __syncthreads();
    #pragma unroll
    for (int kk = 0; kk < BK; ++kk) {
      float x0 = Xs[kk][ty*2], x1 = Xs[kk][ty*2+1];
      #pragma unroll
      for (int g = 0; g < 4; ++g) {
        float w = Ws[kk][g*16 + tx];
        acc[0][g] += x0*w;
        acc[1][g] += x1*w;
      }
    }
    __syncthreads();
  }
  #pragma unroll
  for (int i = 0; i < 2; ++i) {
    int r = row0 + ty*2 + i;
    int j = j0 + tx;
    size_t grow = ((size_t)r*TC + tl)*(4*H_);
    float iv = acc[i][0] + Gchunk[grow + 0*H_ + j];
    float fv = acc[i][1] + Gchunk[grow + 1*H_ + j];
    float gv = acc[i][2] + Gchunk[grow + 2*H_ + j];
    float ov = acc[i][3] + Gchunk[grow + 3*H_ + j];
    float cold = Cprev ? Cprev[(size_t)r*(L_*H_) + j] : 0.f;
    float cnew = sigm(fv)*cold + sigm(iv)*tanhf(gv);
    float hnew = sigm(ov)*tanhf(cnew);
    Hout[(size_t)r*(L_*H_) + j] = hnew;
    Cout[(size_t)r*(L_*H_) + j] = cnew;
  }
}

// ---------------------------------------------------------------------------
extern "C" void kernel_launch(void* const* d_in, const int* in_sizes, int n_in,
                              void* d_out, int out_size, void* d_ws, size_t ws_size,
                              hipStream_t stream)
{
  const float* x   = (const float*)d_in[0];
  const float* Wih = (const float*)d_in[1];
  const float* bih = (const float*)d_in[2];
  const float* Wmx = (const float*)d_in[3];
  const float* bmx = (const float*)d_in[4];
  const float* Wmh = (const float*)d_in[5];
  const float* bmh = (const float*)d_in[6];
  const float* Whm = (const float*)d_in[7];
  const float* bhm = (const float*)d_in[8];
  const float* Wa  = (const float*)d_in[9];
  const float* ba  = (const float*)d_in[10];

  float* out  = (float*)d_out;
  float* hseq = out;                           // (B, L, H)
  float* cseq = out + (size_t)B_*L_*H_;        // (B, L, H)
  float* xt   = out + (size_t)2*B_*L_*H_;      // (B, L, C)

  // Workspace layout (floats): A_chunk (B*TC*H), G_chunk (B*TC*4H), Mt (B*H)
  float* A  = (float*)d_ws;
  float* G  = A + (size_t)B_*TC*H_;
  float* Mt = G + (size_t)B_*TC*4*H_;
  // total = 2.10M + 8.39M + 0.13M floats = ~40.5 MB  (must be <= ws_size)

  // x_tilde: fully parallel (softmax is invariant to the h/C scalar shift)
  xtilde_kernel<<<B_, 256, 0, stream>>>(x, Wa, ba, xt);

  for (int ch = 0; ch < NCHUNK; ++ch) {
    const int t0 = ch * TC;
    // Parallel precompute for this time chunk
    gemm_precompute<<<dim3(H_/64,   (B_*TC)/64), 256, 0, stream>>>(
        x, Wmx, bmx, bmh, A, H_, t0);
    gemm_precompute<<<dim3((4*H_)/64,(B_*TC)/64), 256, 0, stream>>>(
        x, Wih, bih, bhm, G, 4*H_, t0);

    for (int tl = 0; tl < TC; ++tl) {
      const int t = t0 + tl;
      const float* hprev = (t > 0) ? (hseq + (size_t)(t-1)*H_) : hseq;
      const float* cprev = (t > 0) ? (cseq + (size_t)(t-1)*H_) : nullptr;
      mt_kernel<<<dim3(H_/32, B_/32), 256, 0, stream>>>(
          hprev, Wmh, A, tl, Mt, (t > 0) ? H_ : 0);
      gates_cell_kernel<<<dim3(H_/16, B_/32), 256, 0, stream>>>(
          Mt, Whm, G, tl, cprev,
          hseq + (size_t)t*H_, cseq + (size_t)t*H_);
    }
  }
}

// Round 2
// 3651.367 us; speedup vs baseline: 3.1447x; 3.1447x over previous
//
#include <hip/hip_runtime.h>
#include <math.h>

// Dims (fixed)
#define B_ 256
#define L_ 128
#define C_ 256
#define H_ 512
#define N4H 2048          // 4*H
#define TC 16             // time chunk for G2 staging
#define NCHUNK (L_/TC)

// Algebra (mt is not an output, fold it):
//   gates_t = G2_t + h_{t-1} @ W2
//   W2   = Wmh @ Whm                         (one-time, stored transposed [k][j*4+g])
//   Weff = Wih + Wmx @ Whm                   (one-time)
//   beff = bih + bhm + (bmx+bmh) @ Whm       (one-time)
//   G2   = x @ Weff + beff                   (parallel, chunked over time)
//   alpha_t = softmax_c(x_score) is t-invariant -> x_tilde fully parallel.

__device__ __forceinline__ float sigm(float x){ return 1.f/(1.f+expf(-x)); }

// ---------------------------------------------------------------------------
// x_tilde: softmax over C of sum_l x[b,l,c]*Wa_x[l] + ba; xt = alpha * x
// ---------------------------------------------------------------------------
__global__ __launch_bounds__(256) void xtilde_kernel(
    const float* __restrict__ x, const float* __restrict__ Wa,
    const float* __restrict__ ba, float* __restrict__ xt_out)
{
  const int b = blockIdx.x;
  const int c = threadIdx.x;
  const float* Wax = Wa + 2*H_;
  const float* xb  = x + (size_t)b*L_*C_;
  float s = 0.f;
  #pragma unroll 4
  for (int l = 0; l < L_; ++l) s += xb[(size_t)l*C_ + c] * Wax[l];
  s += ba[0];

  __shared__ float red[256];
  red[c] = s; __syncthreads();
  for (int off = 128; off > 0; off >>= 1) {
    if (c < off) red[c] = fmaxf(red[c], red[c+off]);
    __syncthreads();
  }
  const float m = red[0]; __syncthreads();
  const float e = expf(s - m);
  red[c] = e; __syncthreads();
  for (int off = 128; off > 0; off >>= 1) {
    if (c < off) red[c] += red[c+off];
    __syncthreads();
  }
  const float alpha = e / red[0];
  float* ob = xt_out + (size_t)b*L_*C_;
  #pragma unroll 4
  for (int l = 0; l < L_; ++l) ob[(size_t)l*C_ + c] = alpha * xb[(size_t)l*C_ + c];
}

// ---------------------------------------------------------------------------
// Generic fp32 GEMM, 64x64 tile, 4x4/thread, b128 LDS reads.
// t0 >= 0: A-rows are x-chunk rows (gm -> (gm/TC)*L + t0 + gm%TC).
// Out[r, c'] = sum_k A[r,k]*Bm[k,c] (+bias[c]) (+addmat[r,c]);
// permute: c' = (c&511)*4 + (c>>9)   (used to store W2 as [k][j*4+g])
// ---------------------------------------------------------------------------
__global__ __launch_bounds__(256) void gemm64(
    const float* __restrict__ A, int lda, int t0,
    const float* __restrict__ Bm, int N, int K,
    const float* __restrict__ bias, const float* __restrict__ addmat,
    float* __restrict__ Out, int permute)
{
  constexpr int BM=64, BN=64, BK=16, PAD=4;
  __shared__ float Xs[BK][BM+PAD];
  __shared__ float Ws[BK][BN+PAD];
  const int tid = threadIdx.x;
  const int row0 = blockIdx.y*BM, col0 = blockIdx.x*BN;
  const int tx = tid & 15, ty = tid >> 4;
  float acc[4][4] = {};

  for (int k0 = 0; k0 < K; k0 += BK) {
    {
      int m = tid >> 2, q = tid & 3;            // 64 rows x 4 quads
      int gm = row0 + m;
      long grow = (t0 >= 0) ? ((long)(gm/TC)*L_ + t0 + (gm & (TC-1))) : (long)gm;
      const float4 v = *(const float4*)&A[grow*(long)lda + k0 + q*4];
      Xs[q*4+0][m] = v.x; Xs[q*4+1][m] = v.y; Xs[q*4+2][m] = v.z; Xs[q*4+3][m] = v.w;
    }
    {
      int kk = tid >> 4, c4 = tid & 15;         // 16 kk x 16 quads
      *(float4*)&Ws[kk][c4*4] = *(const float4*)&Bm[(long)(k0+kk)*N + col0 + c4*4];
    }
    __syncthreads();
    #pragma unroll
    for (int kk = 0; kk < BK; ++kk) {
      float4 xv = *(const float4*)&Xs[kk][ty*4];
      float4 wv = *(const float4*)&Ws[kk][tx*4];
      const float xs[4] = {xv.x,xv.y,xv.z,xv.w};
      const float ws[4] = {wv.x,wv.y,wv.z,wv.w};
      #pragma unroll
      for (int i=0;i<4;++i)
        #pragma unroll
        for (int j=0;j<4;++j) acc[i][j] += xs[i]*ws[j];
    }
    __syncthreads();
  }
  #pragma unroll
  for (int i=0;i<4;++i) {
    int r = row0 + ty*4 + i;
    #pragma unroll
    for (int j=0;j<4;++j) {
      int c = col0 + tx*4 + j;
      float v = acc[i][j];
      if (bias)   v += bias[c];
      if (addmat) v += addmat[(long)r*N + c];
      int oc = permute ? ((c & 511)*4 + (c >> 9)) : c;
      Out[(long)r*N + oc] = v;
    }
  }
}

// ---------------------------------------------------------------------------
// beff[n] = bih[n] + bhm[n] + sum_k (bmx[k]+bmh[k]) * Whm[k,n]
// ---------------------------------------------------------------------------
__global__ __launch_bounds__(256) void beff_kernel(
    const float* __restrict__ bih, const float* __restrict__ bhm,
    const float* __restrict__ bmx, const float* __restrict__ bmh,
    const float* __restrict__ Whm, float* __restrict__ beff)
{
  int n = blockIdx.x*256 + threadIdx.x;
  float s = bih[n] + bhm[n];
  for (int k = 0; k < H_; ++k) s += (bmx[k]+bmh[k]) * Whm[(long)k*N4H + n];
  beff[n] = s;
}

// ---------------------------------------------------------------------------
// Per-step fused: gates = G2_row + h_{t-1}@W2 ; LSTM cell.
// Tile: 32 batch rows x (16 j x 4 gates). Grid (512/16, 256/32) = 256 blocks.
// W2t layout [k][j*4+g] -> one ds_read_b128 covers the 4 gate weights.
// ---------------------------------------------------------------------------
__global__ __launch_bounds__(256) void step_kernel(
    const float* __restrict__ Hprev,  // row stride L*H (unused if Kdim==0)
    const float* __restrict__ W2t,    // [H][2048] permuted
    const float* __restrict__ G2,     // [(b*TC+tl)][2048]
    int tl, int Kdim,
    const float* __restrict__ Cprev,  // row stride L*H, or null at t=0
    float* __restrict__ Hout, float* __restrict__ Cout)
{
  constexpr int BM=32, BK=32;
  __shared__ float Hs[BK][BM+2];     // pad 34 (even) -> b64 reads aligned
  __shared__ float Ws[BK][64+4];     // pad 68 (mult 4) -> b128 aligned
  const int tid = threadIdx.x;
  const int row0 = blockIdx.y * BM;
  const int j0   = blockIdx.x * 16;
  const int tx = tid & 15, ty = tid >> 4;
  float acc[2][4] = {};

  for (int k0 = 0; k0 < Kdim; k0 += BK) {
    #pragma unroll
    for (int u = 0; u < 4; ++u) {                 // 1024 = 32 m x 32 kk
      int idx = tid + u*256;
      int m = idx >> 5, kk = idx & 31;
      Hs[kk][m] = Hprev[(long)(row0+m)*(L_*H_) + k0 + kk];
    }
    #pragma unroll
    for (int u = 0; u < 2; ++u) {                 // 512 f4 = 32 kk x 16 q
      int idx = tid + u*256;
      int kk = idx >> 4, q4 = idx & 15;
      *(float4*)&Ws[kk][q4*4] =
          *(const float4*)&W2t[(long)(k0+kk)*N4H + j0*4 + q4*4];
    }
    __syncthreads();
    #pragma unroll
    for (int kk = 0; kk < BK; ++kk) {
      float2 xv = *(const float2*)&Hs[kk][ty*2];
      float4 wv = *(const float4*)&Ws[kk][tx*4];
      acc[0][0] += xv.x*wv.x; acc[0][1] += xv.x*wv.y;
      acc[0][2] += xv.x*wv.z; acc[0][3] += xv.x*wv.w;
      acc[1][0] += xv.y*wv.x; acc[1][1] += xv.y*wv.y;
      acc[1][2] += xv.y*wv.z; acc[1][3] += xv.y*wv.w;
    }
    __syncthreads();
  }

  const int j = j0 + tx;
  #pragma unroll
  for (int i = 0; i < 2; ++i) {
    int r = row0 + ty*2 + i;
    long grow = ((long)r*TC + tl)*N4H;
    float iv = acc[i][0] + G2[grow + 0*H_ + j];
    float fv = acc[i][1] + G2[grow + 1*H_ + j];
    float gv = acc[i][2] + G2[grow + 2*H_ + j];
    float ov = acc[i][3] + G2[grow + 3*H_ + j];
    float cold = Cprev ? Cprev[(long)r*(L_*H_) + j] : 0.f;
    float cnew = sigm(fv)*cold + sigm(iv)*tanhf(gv);
    float hnew = sigm(ov)*tanhf(cnew);
    Hout[(long)r*(L_*H_) + j] = hnew;
    Cout[(long)r*(L_*H_) + j] = cnew;
  }
}

// ---------------------------------------------------------------------------
extern "C" void kernel_launch(void* const* d_in, const int* in_sizes, int n_in,
                              void* d_out, int out_size, void* d_ws, size_t ws_size,
                              hipStream_t stream)
{
  const float* x   = (const float*)d_in[0];
  const float* Wih = (const float*)d_in[1];
  const float* bih = (const float*)d_in[2];
  const float* Wmx = (const float*)d_in[3];
  const float* bmx = (const float*)d_in[4];
  const float* Wmh = (const float*)d_in[5];
  const float* bmh = (const float*)d_in[6];
  const float* Whm = (const float*)d_in[7];
  const float* bhm = (const float*)d_in[8];
  const float* Wa  = (const float*)d_in[9];
  const float* ba  = (const float*)d_in[10];

  float* out  = (float*)d_out;
  float* hseq = out;                           // (B, L, H)
  float* cseq = out + (size_t)B_*L_*H_;        // (B, L, H)
  float* xt   = out + (size_t)2*B_*L_*H_;      // (B, L, C)

  // ws: G2 chunk (B*TC*4H = 8.39M f), W2t (H*4H = 1.05M f), beff (2048),
  //     Weff (C*4H = 524K f)  -> total ~39.8 MB
  float* G2   = (float*)d_ws;
  float* W2t  = G2  + (size_t)B_*TC*N4H;
  float* beff = W2t + (size_t)H_*N4H;
  float* Weff = beff + N4H;

  // Fully parallel x_tilde
  xtilde_kernel<<<B_, 256, 0, stream>>>(x, Wa, ba, xt);

  // One-time folds
  beff_kernel<<<N4H/256, 256, 0, stream>>>(bih, bhm, bmx, bmh, Whm, beff);
  gemm64<<<dim3(N4H/64, H_/64), 256, 0, stream>>>(      // W2t = perm(Wmh@Whm)
      Wmh, H_, -1, Whm, N4H, H_, nullptr, nullptr, W2t, 1);
  gemm64<<<dim3(N4H/64, C_/64), 256, 0, stream>>>(      // Weff = Wmx@Whm + Wih
      Wmx, H_, -1, Whm, N4H, H_, nullptr, Wih, Weff, 0);

  for (int ch = 0; ch < NCHUNK; ++ch) {
    const int t0 = ch * TC;
    // G2 chunk = x_chunk @ Weff + beff
    gemm64<<<dim3(N4H/64, (B_*TC)/64), 256, 0, stream>>>(
        x, C_, t0, Weff, N4H, C_, beff, nullptr, G2, 0);

    for (int tl = 0; tl < TC; ++tl) {
      const int t = t0 + tl;
      const float* hprev = (t > 0) ? (hseq + (size_t)(t-1)*H_) : hseq;
      const float* cprev = (t > 0) ? (cseq + (size_t)(t-1)*H_) : nullptr;
      step_kernel<<<dim3(H_/16, B_/32), 256, 0, stream>>>(
          hprev, W2t, G2, tl, (t > 0) ? H_ : 0, cprev,
          hseq + (size_t)t*H_, cseq + (size_t)t*H_);
    }
  }
}

// Round 3
// 3465.299 us; speedup vs baseline: 3.3135x; 1.0537x over previous
//
#include <hip/hip_runtime.h>
#include <math.h>

// Dims (fixed)
#define B_ 256
#define L_ 128
#define C_ 256
#define H_ 512
#define N4H 2048
#define TC 8              // time chunk
#define NCHUNK (L_/TC)    // 16

// Algebra (R2, verified):
//   gates_t = G2_t + h_{t-1} @ W2 ;  W2 = Wmh@Whm ; Weff = Wih + Wmx@Whm
//   beff = bih + bhm + (bmx+bmh)@Whm ; G2 = x@Weff + beff (parallel, chunked)
//   alpha_t t-invariant -> x_tilde fully parallel.
// R3: all hot GEMMs via split-bf16 MFMA (hi+lo, drop lo*lo; fp32-like accuracy).
// Gate-permuted column space n' = j*4 + g so one lane-quad holds i,f,g,o of j.
// Weights/h stored [col][k] bf16 -> MFMA frags are direct 16B global loads (no LDS).

typedef float f32x4 __attribute__((ext_vector_type(4)));
typedef short short8 __attribute__((ext_vector_type(8)));

__device__ __forceinline__ float sigm(float x){ return 1.f/(1.f+expf(-x)); }

__device__ __forceinline__ void splitbf(float v, short& hi, short& lo) {
  union { float f; unsigned u; } a; a.f = v;
  unsigned r = (a.u + 0x7fffu + ((a.u >> 16) & 1u)) >> 16;
  hi = (short)r;
  union { unsigned u; float f; } h; h.u = r << 16;
  float res = v - h.f;
  union { float f; unsigned u; } b; b.f = res;
  unsigned r2 = (b.u + 0x7fffu + ((b.u >> 16) & 1u)) >> 16;
  lo = (short)r2;
}

// ---------------------------------------------------------------------------
// x_tilde (unchanged from R2, verified)
// ---------------------------------------------------------------------------
__global__ __launch_bounds__(256) void xtilde_kernel(
    const float* __restrict__ x, const float* __restrict__ Wa,
    const float* __restrict__ ba, float* __restrict__ xt_out)
{
  const int b = blockIdx.x;
  const int c = threadIdx.x;
  const float* Wax = Wa + 2*H_;
  const float* xb  = x + (size_t)b*L_*C_;
  float s = 0.f;
  #pragma unroll 4
  for (int l = 0; l < L_; ++l) s += xb[(size_t)l*C_ + c] * Wax[l];
  s += ba[0];
  __shared__ float red[256];
  red[c] = s; __syncthreads();
  for (int off = 128; off > 0; off >>= 1) {
    if (c < off) red[c] = fmaxf(red[c], red[c+off]);
    __syncthreads();
  }
  const float m = red[0]; __syncthreads();
  const float e = expf(s - m);
  red[c] = e; __syncthreads();
  for (int off = 128; off > 0; off >>= 1) {
    if (c < off) red[c] += red[c+off];
    __syncthreads();
  }
  const float alpha = e / red[0];
  float* ob = xt_out + (size_t)b*L_*C_;
  #pragma unroll 4
  for (int l = 0; l < L_; ++l) ob[(size_t)l*C_ + c] = alpha * xb[(size_t)l*C_ + c];
}

// ---------------------------------------------------------------------------
// One-time fold GEMM (R2's verified gemm64 body). Epilogue:
//   ohi!=null : split-bf16, permute-transpose write  ohi[n'* outK + r], n'=(c&511)*4+(c>>9)
//   else      : fp32 Out[r*N + c] (+bias)
// addmat added in both modes.
// ---------------------------------------------------------------------------
__global__ __launch_bounds__(256) void gemm64(
    const float* __restrict__ A, int lda,
    const float* __restrict__ Bm, int N, int K,
    const float* __restrict__ bias, const float* __restrict__ addmat,
    float* __restrict__ Out, short* __restrict__ ohi, short* __restrict__ olo,
    int outK)
{
  constexpr int BM=64, BN=64, BK=16, PAD=4;
  __shared__ float Xs[BK][BM+PAD];
  __shared__ float Ws[BK][BN+PAD];
  const int tid = threadIdx.x;
  const int row0 = blockIdx.y*BM, col0 = blockIdx.x*BN;
  const int tx = tid & 15, ty = tid >> 4;
  float acc[4][4] = {};

  for (int k0 = 0; k0 < K; k0 += BK) {
    {
      int m = tid >> 2, q = tid & 3;
      const float4 v = *(const float4*)&A[(long)(row0+m)*lda + k0 + q*4];
      Xs[q*4+0][m] = v.x; Xs[q*4+1][m] = v.y; Xs[q*4+2][m] = v.z; Xs[q*4+3][m] = v.w;
    }
    {
      int kk = tid >> 4, c4 = tid & 15;
      *(float4*)&Ws[kk][c4*4] = *(const float4*)&Bm[(long)(k0+kk)*N + col0 + c4*4];
    }
    __syncthreads();
    #pragma unroll
    for (int kk = 0; kk < BK; ++kk) {
      float4 xv = *(const float4*)&Xs[kk][ty*4];
      float4 wv = *(const float4*)&Ws[kk][tx*4];
      const float xs[4] = {xv.x,xv.y,xv.z,xv.w};
      const float ws[4] = {wv.x,wv.y,wv.z,wv.w};
      #pragma unroll
      for (int i=0;i<4;++i)
        #pragma unroll
        for (int j=0;j<4;++j) acc[i][j] += xs[i]*ws[j];
    }
    __syncthreads();
  }
  #pragma unroll
  for (int i=0;i<4;++i) {
    int r = row0 + ty*4 + i;
    #pragma unroll
    for (int j=0;j<4;++j) {
      int c = col0 + tx*4 + j;
      float v = acc[i][j];
      if (addmat) v += addmat[(long)r*N + c];
      if (ohi) {
        int oc = (c & 511)*4 + (c >> 9);
        short hi, lo; splitbf(v, hi, lo);
        ohi[(long)oc*outK + r] = hi;
        olo[(long)oc*outK + r] = lo;
      } else {
        if (bias) v += bias[c];
        Out[(long)r*N + c] = v;
      }
    }
  }
}

// ---------------------------------------------------------------------------
// beff_p[n'] = bih[n]+bhm[n] + sum_k (bmx[k]+bmh[k])*Whm[k,n], permuted store
// ---------------------------------------------------------------------------
__global__ __launch_bounds__(256) void beff_kernel(
    const float* __restrict__ bih, const float* __restrict__ bhm,
    const float* __restrict__ bmx, const float* __restrict__ bmh,
    const float* __restrict__ Whm, float* __restrict__ beff)
{
  int n = blockIdx.x*256 + threadIdx.x;
  float s = bih[n] + bhm[n];
  for (int k = 0; k < H_; ++k) s += (bmx[k]+bmh[k]) * Whm[(long)k*N4H + n];
  beff[(n & 511)*4 + (n >> 9)] = s;
}

// ---------------------------------------------------------------------------
// Split x chunk into bf16 hi/lo, rows r = b*TC+tl -> x row b*L + t0+tl
// ---------------------------------------------------------------------------
__global__ __launch_bounds__(256) void xsplit_kernel(
    const float* __restrict__ x, short* __restrict__ xh, short* __restrict__ xl,
    int t0)
{
  int idx = (blockIdx.x*256 + threadIdx.x)*4;   // over 2048*256 elems
  int r = idx >> 8, c = idx & 255;
  int b = r >> 3, tl = r & 7;                   // TC=8
  const float4 v = *(const float4*)&x[((long)b*L_ + t0 + tl)*C_ + c];
  short4 h, l;
  splitbf(v.x, h.x, l.x); splitbf(v.y, h.y, l.y);
  splitbf(v.z, h.z, l.z); splitbf(v.w, h.w, l.w);
  *(short4*)&xh[(long)r*C_ + c] = h;
  *(short4*)&xl[(long)r*C_ + c] = l;
}

// ---------------------------------------------------------------------------
// G2 chunk GEMM via split-bf16 MFMA, no LDS.
// M=2048 chunk rows, N'=2048, K=256. Block: 128 rows x 64 n', 512 thr (8 waves).
// ---------------------------------------------------------------------------
__global__ __launch_bounds__(512) void g2_mfma(
    const short* __restrict__ xh, const short* __restrict__ xl,   // [2048][256]
    const short* __restrict__ Wh, const short* __restrict__ Wl,   // [n'][256]
    const float* __restrict__ beff, float* __restrict__ G2)
{
  const int tid = threadIdx.x;
  const int lane = tid & 63, w = tid >> 6;
  const int row0 = blockIdx.y*128 + w*16;
  const int n0   = blockIdx.x*64;
  const int lc = lane & 15, lk = lane >> 4;

  f32x4 acc[4] = {};
  const short* pa = xh + (long)(row0+lc)*C_ + lk*8;
  const short* pl = xl + (long)(row0+lc)*C_ + lk*8;
  #pragma unroll 2
  for (int k0 = 0; k0 < C_; k0 += 32) {
    short8 a  = *(const short8*)(pa + k0);
    short8 al = *(const short8*)(pl + k0);
    #pragma unroll
    for (int tn = 0; tn < 4; ++tn) {
      const long wrow = (long)(n0 + tn*16 + lc)*C_ + lk*8 + k0;
      short8 bh = *(const short8*)(Wh + wrow);
      short8 bl = *(const short8*)(Wl + wrow);
      acc[tn] = __builtin_amdgcn_mfma_f32_16x16x32_bf16(al, bh, acc[tn], 0,0,0);
      acc[tn] = __builtin_amdgcn_mfma_f32_16x16x32_bf16(a,  bl, acc[tn], 0,0,0);
      acc[tn] = __builtin_amdgcn_mfma_f32_16x16x32_bf16(a,  bh, acc[tn], 0,0,0);
    }
    __syncthreads();   // convoy waves for L1 reuse of W frags
  }
  #pragma unroll
  for (int tn = 0; tn < 4; ++tn) {
    int nb = n0 + tn*16 + lc;
    float bv = beff[nb];
    #pragma unroll
    for (int r4 = 0; r4 < 4; ++r4) {
      int row = row0 + lk*4 + r4;
      G2[(long)row*N4H + nb] = acc[tn][r4] + bv;
    }
  }
}

// ---------------------------------------------------------------------------
// Per-step: gates = G2_row + h_{t-1}@W2 (split-bf16 MFMA, no LDS) ; LSTM cell.
// Block: 32 rows x 64 n', 256 thr (4 waves). Grid (32, 8) = 256 blocks.
// Wave: 16-row strip x 32 n' (2 tiles). Quad-shuffle gathers i,f,g,o.
// ---------------------------------------------------------------------------
__global__ __launch_bounds__(256) void step_mfma(
    const short* __restrict__ Hhi, const short* __restrict__ Hlo, // prev h bufs [256][512]
    const short* __restrict__ W2hi, const short* __restrict__ W2lo, // [n'][512]
    const float* __restrict__ G2,     // [b*TC+tl][2048]
    const float* __restrict__ cseq,   // output base (B,L,H)
    float* __restrict__ hseq, float* __restrict__ cout_,
    short* __restrict__ HhiW, short* __restrict__ HloW,             // cur h bufs
    int tl, int t)
{
  const int tid = threadIdx.x;
  const int lane = tid & 63, w = tid >> 6;
  const int row0 = blockIdx.y*32 + (w & 1)*16;
  const int n0   = blockIdx.x*64 + (w >> 1)*32;
  const int lc = lane & 15, lk = lane >> 4;

  f32x4 acc0 = {}, acc1 = {};
  if (t > 0) {
    const short* pa  = Hhi  + (long)(row0+lc)*H_ + lk*8;
    const short* pl  = Hlo  + (long)(row0+lc)*H_ + lk*8;
    const short* pb0 = W2hi + (long)(n0+lc)*H_ + lk*8;
    const short* pc0 = W2lo + (long)(n0+lc)*H_ + lk*8;
    const short* pb1 = W2hi + (long)(n0+16+lc)*H_ + lk*8;
    const short* pc1 = W2lo + (long)(n0+16+lc)*H_ + lk*8;
    #pragma unroll 4
    for (int k0 = 0; k0 < H_; k0 += 32) {
      short8 a   = *(const short8*)(pa + k0);
      short8 al  = *(const short8*)(pl + k0);
      short8 b0h = *(const short8*)(pb0 + k0);
      short8 b0l = *(const short8*)(pc0 + k0);
      short8 b1h = *(const short8*)(pb1 + k0);
      short8 b1l = *(const short8*)(pc1 + k0);
      acc0 = __builtin_amdgcn_mfma_f32_16x16x32_bf16(al, b0h, acc0, 0,0,0);
      acc0 = __builtin_amdgcn_mfma_f32_16x16x32_bf16(a,  b0l, acc0, 0,0,0);
      acc0 = __builtin_amdgcn_mfma_f32_16x16x32_bf16(a,  b0h, acc0, 0,0,0);
      acc1 = __builtin_amdgcn_mfma_f32_16x16x32_bf16(al, b1h, acc1, 0,0,0);
      acc1 = __builtin_amdgcn_mfma_f32_16x16x32_bf16(a,  b1l, acc1, 0,0,0);
      acc1 = __builtin_amdgcn_mfma_f32_16x16x32_bf16(a,  b1h, acc1, 0,0,0);
    }
  }

  #pragma unroll
  for (int tile = 0; tile < 2; ++tile) {
    const f32x4 av = tile ? acc1 : acc0;
    const int nb = n0 + tile*16 + lc;          // this lane's n' = 4j+g
    #pragma unroll
    for (int r4 = 0; r4 < 4; ++r4) {
      const int r = row0 + lk*4 + r4;
      float v = av[r4] + G2[((long)r*TC + tl)*N4H + nb];
      const int qb = lane & ~3;
      float iv = __shfl(v, qb+0, 64);
      float fv = __shfl(v, qb+1, 64);
      float gv = __shfl(v, qb+2, 64);
      float ov = __shfl(v, qb+3, 64);
      if ((lane & 3) == 0) {
        const int j = nb >> 2;
        float cold = (t > 0) ? cseq[((long)r*L_ + (t-1))*H_ + j] : 0.f;
        float cnew = sigm(fv)*cold + sigm(iv)*tanhf(gv);
        float hnew = sigm(ov)*tanhf(cnew);
        cout_[((long)r*L_ + t)*H_ + j] = cnew;
        hseq [((long)r*L_ + t)*H_ + j] = hnew;
        short hh, hl; splitbf(hnew, hh, hl);
        HhiW[(long)r*H_ + j] = hh;
        HloW[(long)r*H_ + j] = hl;
      }
    }
  }
}

// ---------------------------------------------------------------------------
extern "C" void kernel_launch(void* const* d_in, const int* in_sizes, int n_in,
                              void* d_out, int out_size, void* d_ws, size_t ws_size,
                              hipStream_t stream)
{
  const float* x   = (const float*)d_in[0];
  const float* Wih = (const float*)d_in[1];
  const float* bih = (const float*)d_in[2];
  const float* Wmx = (const float*)d_in[3];
  const float* bmx = (const float*)d_in[4];
  const float* Wmh = (const float*)d_in[5];
  const float* bmh = (const float*)d_in[6];
  const float* Whm = (const float*)d_in[7];
  const float* bhm = (const float*)d_in[8];
  const float* Wa  = (const float*)d_in[9];
  const float* ba  = (const float*)d_in[10];

  float* out  = (float*)d_out;
  float* hseq = out;                           // (B, L, H)
  float* cseq = out + (size_t)B_*L_*H_;        // (B, L, H)
  float* xt   = out + (size_t)2*B_*L_*H_;      // (B, L, C)

  // ws carve (all 16B aligned; total ~26 MB)
  float* G2     = (float*)d_ws;                // 4,194,304 f
  float* beff_p = G2 + (size_t)B_*TC*N4H;      // 2048 f
  short* W2hi   = (short*)(beff_p + N4H);      // [2048][512]
  short* W2lo   = W2hi + (size_t)N4H*H_;
  short* Wfh    = W2lo + (size_t)N4H*H_;       // [2048][256]
  short* Wfl    = Wfh + (size_t)N4H*C_;
  short* xh     = Wfl + (size_t)N4H*C_;        // [2048][256]
  short* xl_    = xh + (size_t)B_*TC*C_;
  short* Hbh    = xl_ + (size_t)B_*TC*C_;      // 2 bufs [256][512]
  short* Hbl    = Hbh + (size_t)2*B_*H_;

  xtilde_kernel<<<B_, 256, 0, stream>>>(x, Wa, ba, xt);
  beff_kernel<<<N4H/256, 256, 0, stream>>>(bih, bhm, bmx, bmh, Whm, beff_p);
  // W2 = Wmh@Whm -> split/permute/transpose [n'][512]
  gemm64<<<dim3(N4H/64, H_/64), 256, 0, stream>>>(
      Wmh, H_, Whm, N4H, H_, nullptr, nullptr, nullptr, W2hi, W2lo, H_);
  // Weff = Wmx@Whm + Wih -> split/permute/transpose [n'][256]
  gemm64<<<dim3(N4H/64, C_/64), 256, 0, stream>>>(
      Wmx, H_, Whm, N4H, H_, nullptr, Wih, nullptr, Wfh, Wfl, C_);

  for (int ch = 0; ch < NCHUNK; ++ch) {
    const int t0 = ch * TC;
    xsplit_kernel<<<(B_*TC*C_/4)/256, 256, 0, stream>>>(x, xh, xl_, t0);
    g2_mfma<<<dim3(N4H/64, (B_*TC)/128), 512, 0, stream>>>(
        xh, xl_, Wfh, Wfl, beff_p, G2);

    for (int tl = 0; tl < TC; ++tl) {
      const int t = t0 + tl;
      const int rb = (t & 1) ^ 1, wb = t & 1;
      step_mfma<<<dim3(N4H/64, B_/32), 256, 0, stream>>>(
          Hbh + (size_t)rb*B_*H_, Hbl + (size_t)rb*B_*H_,
          W2hi, W2lo, G2, cseq, hseq, cseq,
          Hbh + (size_t)wb*B_*H_, Hbl + (size_t)wb*B_*H_,
          tl, t);
    }
  }
}